// Round 6
// baseline (5707.285 us; speedup 1.0000x reference)
//
#include <hip/hip_runtime.h>

// Persistent cooperative GRU decoder. B=256, I=512, H=1024, S=128.
// One kernel, 256 WGs (1/CU). Gate weights (fp16) live in LDS per-WG.
// R5: replace global grid barriers (15.5us each: 256-deep serialized RMW on
// one line) with per-rowgroup flag sync: 64 parallel RELEASE stores to
// distinct flags + per-lane RELAXED polling + one ACQUIRE fence.

#define HID 1024
#define INP 512
#define BATCH 256
#define SEQ 128
#define NWG 256
#define NTHR 256
#define WIH_LD 520   // 512 + 8 pad
#define WHH_LD 1032  // 1024 + 8 pad

typedef _Float16 f16x8 __attribute__((ext_vector_type(8)));
typedef float f32x4 __attribute__((ext_vector_type(4)));

__device__ __forceinline__ float fast_sigmoid(float x) {
    return 1.0f / (1.0f + __expf(-x));
}
__device__ __forceinline__ float fast_tanh(float x) {
    return 1.0f - 2.0f / (__expf(2.0f * x) + 1.0f);
}

struct Params {
    const float *ehid, *Wih, *Whh, *bih, *bhh, *Wout, *bout;
    const float *Wm1, *bm1, *Wm2, *bm2, *Wc1, *bc1, *Wc2, *bc2;
    _Float16 *WoutH, *Wm1H, *Wc1H;
    float *h32; _Float16 *h16; _Float16 *outs;
    int *bar; int *flagA; int *flagB; float *dout;
};

// One-shot sense-reversing grid barrier (startup only).
__device__ __forceinline__ void gbar(int* bar) {
    __syncthreads();
    if (threadIdx.x == 0) {
        int g = __hip_atomic_load(bar + 32, __ATOMIC_RELAXED, __HIP_MEMORY_SCOPE_AGENT);
        int a = __hip_atomic_fetch_add(bar, 1, __ATOMIC_RELEASE, __HIP_MEMORY_SCOPE_AGENT);
        if (a == NWG - 1) {
            __hip_atomic_store(bar, 0, __ATOMIC_RELAXED, __HIP_MEMORY_SCOPE_AGENT);
            __hip_atomic_fetch_add(bar + 32, 1, __ATOMIC_RELEASE, __HIP_MEMORY_SCOPE_AGENT);
        } else {
            while (__hip_atomic_load(bar + 32, __ATOMIC_RELAXED, __HIP_MEMORY_SCOPE_AGENT) == g) {
                __builtin_amdgcn_s_sleep(2);
            }
        }
        __builtin_amdgcn_fence(__ATOMIC_ACQUIRE, "agent");
    }
    __syncthreads();
}

// Wait until all 64 packed flags reach `target`. Per-lane relaxed polls
// (4 cache lines per poll), then one agent acquire fence (per wave).
__device__ __forceinline__ void wait_flags64(const int* flags, int target) {
    const int lane = threadIdx.x & 63;
    while (true) {
        int v = __hip_atomic_load(flags + lane, __ATOMIC_RELAXED, __HIP_MEMORY_SCOPE_AGENT);
        if (!__any(v < target)) break;
        __builtin_amdgcn_s_sleep(1);
    }
    __builtin_amdgcn_fence(__ATOMIC_ACQUIRE, "agent");
}

// Publish: all waves' global stores are in our XCD L2 after __syncthreads;
// thread0's RELEASE store emits one buffer_wbl2 (pushes them to the
// coherent point) + the flag store.
__device__ __forceinline__ void set_flag(int* flag, int val) {
    __syncthreads();
    if (threadIdx.x == 0)
        __hip_atomic_store(flag, val, __ATOMIC_RELEASE, __HIP_MEMORY_SCOPE_AGENT);
}

__global__ __launch_bounds__(NTHR, 1) void gru_persistent(Params p) {
    __shared__ __align__(16) char smraw[3 * 16 * WIH_LD * 2 + 3 * 16 * WHH_LD * 2];
    __shared__ float red[2 * 16 * 16];
    _Float16* wih_s = (_Float16*)smraw;
    _Float16* whh_s = (_Float16*)(smraw + 3 * 16 * WIH_LD * 2);
    _Float16* hid_s = (_Float16*)smraw;  // heads overlay

    const int w = blockIdx.x;
    const int wave = threadIdx.x >> 6;
    const int lane = threadIdx.x & 63;
    const int l15 = lane & 15;
    const int kq = lane >> 4;

    // ---- prep: fp16 conversions (grid-stride over all WGs) ----
    {
        const int tid = w * NTHR + threadIdx.x;
        const int nth = NWG * NTHR;
        for (int i = tid; i < INP * HID / 4; i += nth) {
            float4 v = ((const float4*)p.Wout)[i];
            _Float16* d = p.WoutH + i * 4;
            d[0] = (_Float16)v.x; d[1] = (_Float16)v.y; d[2] = (_Float16)v.z; d[3] = (_Float16)v.w;
        }
        for (int i = tid; i < 128 * INP / 4; i += nth) {
            float4 v = ((const float4*)p.Wm1)[i];
            _Float16* d = p.Wm1H + i * 4;
            d[0] = (_Float16)v.x; d[1] = (_Float16)v.y; d[2] = (_Float16)v.z; d[3] = (_Float16)v.w;
            float4 u = ((const float4*)p.Wc1)[i];
            _Float16* e = p.Wc1H + i * 4;
            e[0] = (_Float16)u.x; e[1] = (_Float16)u.y; e[2] = (_Float16)u.z; e[3] = (_Float16)u.w;
        }
        for (int i = tid; i < BATCH * HID / 4; i += nth) {
            float4 v = ((const float4*)p.ehid)[i];
            ((float4*)p.h32)[i] = v;
            _Float16* d = p.h16 + i * 4;
            d[0] = (_Float16)v.x; d[1] = (_Float16)v.y; d[2] = (_Float16)v.z; d[3] = (_Float16)v.w;
        }
    }

    // ---- load this WG's gate-weight slice into LDS (fp32 -> fp16) ----
    const int jj = w >> 2;   // 0..63: 16-col slice of H
    const int b4 = w & 3;    // 0..3 : 64-row group of B  (= rowgroup g)
    for (int i = threadIdx.x; i < 3 * 16 * (INP / 4); i += NTHR) {
        int gi = i / (16 * (INP / 4));
        int rr = (i / (INP / 4)) % 16;
        int kk = (i % (INP / 4)) * 4;
        float4 v = *(const float4*)(p.Wih + ((size_t)(gi * HID + jj * 16 + rr)) * INP + kk);
        _Float16* d = &wih_s[(gi * 16 + rr) * WIH_LD + kk];
        d[0] = (_Float16)v.x; d[1] = (_Float16)v.y; d[2] = (_Float16)v.z; d[3] = (_Float16)v.w;
    }
    for (int i = threadIdx.x; i < 3 * 16 * (HID / 4); i += NTHR) {
        int gi = i / (16 * (HID / 4));
        int rr = (i / (HID / 4)) % 16;
        int kk = (i % (HID / 4)) * 4;
        float4 v = *(const float4*)(p.Whh + ((size_t)(gi * HID + jj * 16 + rr)) * HID + kk);
        _Float16* d = &whh_s[(gi * 16 + rr) * WHH_LD + kk];
        d[0] = (_Float16)v.x; d[1] = (_Float16)v.y; d[2] = (_Float16)v.z; d[3] = (_Float16)v.w;
    }

    gbar(p.bar);  // startup: prep + LDS slices ready everywhere

    // hoisted per-lane constants
    const int jc = jj * 16 + l15;
    const float brr = p.bih[jc] + p.bhh[jc];
    const float bzz = p.bih[HID + jc] + p.bhh[HID + jc];
    const float bin = p.bih[2 * HID + jc];
    const float bhn = p.bhh[2 * HID + jc];
    const int grow  = b4 * 64 + wave * 16 + l15;
    const int gcrow = b4 * 64 + wave * 16 + kq * 4;

    const int ort = w >> 4;                           // outproj: 16-row tile
    const int oct = w & 15;                           // outproj: 32-col tile
    const int og  = w >> 6;                           // outproj rowgroup (ort>>2)
    const int csub = wave & 1;
    const int khalf = wave >> 1;
    const int orow = ort * 16 + l15;
    const int ocol = oct * 32 + csub * 16 + l15;
    const float obout = p.bout[ocol];

    int* myFlagA = p.flagA + b4 * 64 + jj;                       // gates producer flag
    int* myFlagB = p.flagB + og * 64 + (ort & 3) * 16 + oct;     // outproj producer flag
    const int* grpFlagB = p.flagB + b4 * 64;                     // gates consumer group
    const int* grpFlagA = p.flagA + og * 64;                     // outproj consumer group

    for (int t = 0; t < SEQ; ++t) {
        const int cur = t & 1, nxt = 1 - cur;
        const float*    h32p = p.h32 + (size_t)cur * BATCH * HID;
        float*          h32n = p.h32 + (size_t)nxt * BATCH * HID;
        const _Float16* h16p = p.h16 + (size_t)cur * BATCH * HID;
        _Float16*       h16n = p.h16 + (size_t)nxt * BATCH * HID;

        // ---- phase A: gates (needs outs(t-1) + h'(t-1) of rowgroup b4) ----
        if (t > 0) wait_flags64(grpFlagB, t);

        f32x4 ar = {0.f,0.f,0.f,0.f}, az = {0.f,0.f,0.f,0.f};
        f32x4 ai = {0.f,0.f,0.f,0.f}, ah = {0.f,0.f,0.f,0.f};
        if (t > 0) {
            const _Float16* xp = p.outs + ((size_t)grow * SEQ + (t - 1)) * INP + kq * 8;
            #pragma unroll 4
            for (int kk = 0; kk < INP; kk += 32) {
                f16x8 a = *(const f16x8*)(xp + kk);
                #pragma unroll
                for (int q = 0; q < 8; ++q) a[q] = a[q] > (_Float16)0.f ? a[q] : (_Float16)0.f;
                f16x8 br = *(const f16x8*)&wih_s[(0 * 16 + l15) * WIH_LD + kk + kq * 8];
                f16x8 bz = *(const f16x8*)&wih_s[(1 * 16 + l15) * WIH_LD + kk + kq * 8];
                f16x8 bn = *(const f16x8*)&wih_s[(2 * 16 + l15) * WIH_LD + kk + kq * 8];
                ar = __builtin_amdgcn_mfma_f32_16x16x32_f16(a, br, ar, 0, 0, 0);
                az = __builtin_amdgcn_mfma_f32_16x16x32_f16(a, bz, az, 0, 0, 0);
                ai = __builtin_amdgcn_mfma_f32_16x16x32_f16(a, bn, ai, 0, 0, 0);
            }
        }
        {
            const _Float16* hp = h16p + (size_t)grow * HID + kq * 8;
            #pragma unroll 4
            for (int kk = 0; kk < HID; kk += 32) {
                f16x8 a = *(const f16x8*)(hp + kk);
                f16x8 br = *(const f16x8*)&whh_s[(0 * 16 + l15) * WHH_LD + kk + kq * 8];
                f16x8 bz = *(const f16x8*)&whh_s[(1 * 16 + l15) * WHH_LD + kk + kq * 8];
                f16x8 bn = *(const f16x8*)&whh_s[(2 * 16 + l15) * WHH_LD + kk + kq * 8];
                ar = __builtin_amdgcn_mfma_f32_16x16x32_f16(a, br, ar, 0, 0, 0);
                az = __builtin_amdgcn_mfma_f32_16x16x32_f16(a, bz, az, 0, 0, 0);
                ah = __builtin_amdgcn_mfma_f32_16x16x32_f16(a, bn, ah, 0, 0, 0);
            }
        }
        #pragma unroll
        for (int i = 0; i < 4; ++i) {
            int r = gcrow + i;
            float rr = fast_sigmoid(ar[i] + brr);
            float zz = fast_sigmoid(az[i] + bzz);
            float nn = fast_tanh(ai[i] + bin + rr * (ah[i] + bhn));
            float hold = h32p[(size_t)r * HID + jc];
            float hv = (1.0f - zz) * nn + zz * hold;
            h32n[(size_t)r * HID + jc] = hv;
            h16n[(size_t)r * HID + jc] = (_Float16)hv;
        }

        set_flag(myFlagA, t + 1);          // h'(t) rows of group b4, slice jj: done

        // ---- phase B: outproj (needs h'(t) of rowgroup og) ----
        wait_flags64(grpFlagA, t + 1);
        {
            f32x4 acc = {0.f,0.f,0.f,0.f};
            const _Float16* ap = h16n + (size_t)orow * HID + khalf * 512 + kq * 8;
            const _Float16* bp = p.WoutH + (size_t)ocol * HID + khalf * 512 + kq * 8;
            #pragma unroll 4
            for (int kk = 0; kk < 512; kk += 32) {
                f16x8 a = *(const f16x8*)(ap + kk);
                f16x8 b = *(const f16x8*)(bp + kk);
                acc = __builtin_amdgcn_mfma_f32_16x16x32_f16(a, b, acc, 0, 0, 0);
            }
            if (khalf == 1) {
                #pragma unroll
                for (int i = 0; i < 4; ++i)
                    red[(csub * 16 + kq * 4 + i) * 16 + l15] = acc[i];
            }
            __syncthreads();
            if (khalf == 0) {
                #pragma unroll
                for (int i = 0; i < 4; ++i) {
                    float v = acc[i] + red[(csub * 16 + kq * 4 + i) * 16 + l15];
                    p.outs[((size_t)(ort * 16 + kq * 4 + i) * SEQ + t) * INP + ocol] =
                        (_Float16)(v + obout);
                }
            }
        }

        set_flag(myFlagB, t + 1);          // outs(t) tile (ort,oct): done
    }

    // ---- heads: WG w handles batch element b = w ----
    {
        const int b = w;
        wait_flags64(p.flagB + (b >> 6) * 64, SEQ);   // all outs rows of b's group
        const size_t rowbase = (size_t)b * SEQ;
        for (int head = 0; head < 2; ++head) {
            const _Float16* W1 = head ? p.Wc1H : p.Wm1H;
            const float* b1 = head ? p.bc1 : p.bm1;
            f32x4 acc[2][8];
            #pragma unroll
            for (int rf = 0; rf < 2; ++rf)
                #pragma unroll
                for (int ct = 0; ct < 8; ++ct) acc[rf][ct] = (f32x4){0.f,0.f,0.f,0.f};
            for (int kk = 0; kk < INP; kk += 32) {
                f16x8 a0 = *(const f16x8*)(p.outs + (rowbase + wave * 32 + l15) * INP + kk + kq * 8);
                f16x8 a1 = *(const f16x8*)(p.outs + (rowbase + wave * 32 + 16 + l15) * INP + kk + kq * 8);
                #pragma unroll
                for (int ct = 0; ct < 8; ++ct) {
                    f16x8 bb = *(const f16x8*)(W1 + (size_t)(ct * 16 + l15) * INP + kk + kq * 8);
                    acc[0][ct] = __builtin_amdgcn_mfma_f32_16x16x32_f16(a0, bb, acc[0][ct], 0, 0, 0);
                    acc[1][ct] = __builtin_amdgcn_mfma_f32_16x16x32_f16(a1, bb, acc[1][ct], 0, 0, 0);
                }
            }
            __syncthreads();
            #pragma unroll
            for (int rf = 0; rf < 2; ++rf) {
                int rl = wave * 32 + rf * 16 + kq * 4;
                #pragma unroll
                for (int ct = 0; ct < 8; ++ct) {
                    int col = ct * 16 + l15;
                    float bb1 = b1[col];
                    #pragma unroll
                    for (int i = 0; i < 4; ++i) {
                        float v = acc[rf][ct][i] + bb1;
                        hid_s[(rl + i) * 136 + col] = (_Float16)(v > 0.f ? v : 0.f);
                    }
                }
            }
            __syncthreads();
            if (threadIdx.x < 128) {
                int srow = threadIdx.x;
                if (head == 0) {
                    float a0 = p.bm2[0], a1 = p.bm2[1], a2 = p.bm2[2];
                    for (int k = 0; k < 128; ++k) {
                        float hv = (float)hid_s[srow * 136 + k];
                        a0 += hv * p.Wm2[k];
                        a1 += hv * p.Wm2[128 + k];
                        a2 += hv * p.Wm2[256 + k];
                    }
                    size_t o = ((size_t)b * 128 + srow) * 3;
                    p.dout[o] = a0; p.dout[o + 1] = a1; p.dout[o + 2] = a2;
                } else {
                    float a[6];
                    #pragma unroll
                    for (int m = 0; m < 6; ++m) a[m] = p.bc2[m];
                    for (int k = 0; k < 128; ++k) {
                        float hv = (float)hid_s[srow * 136 + k];
                        #pragma unroll
                        for (int m = 0; m < 6; ++m) a[m] += hv * p.Wc2[m * 128 + k];
                    }
                    size_t o = (size_t)BATCH * SEQ * 3 + ((size_t)b * 128 + srow) * 6;
                    #pragma unroll
                    for (int m = 0; m < 6; ++m) p.dout[o + m] = a[m];
                }
            }
            __syncthreads();
        }
    }
}

extern "C" void kernel_launch(void* const* d_in, const int* in_sizes, int n_in,
                              void* d_out, int out_size, void* d_ws, size_t ws_size,
                              hipStream_t stream) {
    (void)in_sizes; (void)n_in; (void)out_size; (void)ws_size;
    Params prm;
    prm.ehid = (const float*)d_in[1];
    prm.Wih  = (const float*)d_in[2];
    prm.Whh  = (const float*)d_in[3];
    prm.bih  = (const float*)d_in[4];
    prm.bhh  = (const float*)d_in[5];
    prm.Wout = (const float*)d_in[6];
    prm.bout = (const float*)d_in[7];
    prm.Wm1  = (const float*)d_in[8];
    prm.bm1  = (const float*)d_in[9];
    prm.Wm2  = (const float*)d_in[10];
    prm.bm2  = (const float*)d_in[11];
    prm.Wc1  = (const float*)d_in[12];
    prm.bc1  = (const float*)d_in[13];
    prm.Wc2  = (const float*)d_in[14];
    prm.bc2  = (const float*)d_in[15];
    prm.dout = (float*)d_out;

    char* ws = (char*)d_ws;
    prm.bar   = (int*)ws;                                  // 256 B   (startup barrier)
    prm.flagA = (int*)(ws + 256);                          // 1024 B  (256 gate flags)
    prm.flagB = (int*)(ws + 1280);                         // 1024 B  (256 outproj flags)
    prm.WoutH = (_Float16*)(ws + 4096);                    // 1,048,576 B
    prm.Wm1H  = (_Float16*)(ws + 4096 + 1048576);          //   131,072 B
    prm.Wc1H  = (_Float16*)(ws + 4096 + 1179648);          //   131,072 B
    prm.h32   = (float*)   (ws + 4096 + 1310720);          // 2,097,152 B (double buf)
    prm.h16   = (_Float16*)(ws + 4096 + 3407872);          // 1,048,576 B (double buf)
    prm.outs  = (_Float16*)(ws + 4096 + 4456448);          // 33,554,432 B
    // total ~38.0 MB

    hipMemsetAsync(ws, 0, 2304, stream);  // zero barrier + flag state every launch
    void* args[] = { &prm };
    hipLaunchCooperativeKernel((void*)gru_persistent, dim3(NWG), dim3(NTHR),
                               args, 0, stream);
}

// Round 7
// 3827.906 us; speedup vs baseline: 1.4910x; 1.4910x over previous
//
#include <hip/hip_runtime.h>

// Persistent cooperative GRU decoder. B=256, I=512, H=1024, S=128.
// One kernel, 256 WGs (1/CU). Gate weights (fp16) live in LDS per-WG.
// R6: per-rowgroup flag sync (64 producer flags/group).
// R7 fix: poll contention. Only wave 0 polls (4x fewer pollers, coalesced
// to 4 line-reqs/poll), s_sleep(16) throttle (~0.4us between polls), and
// ONE acquire fence per WG per wait instead of 4 (one buffer_inv, not four).

#define HID 1024
#define INP 512
#define BATCH 256
#define SEQ 128
#define NWG 256
#define NTHR 256
#define WIH_LD 520   // 512 + 8 pad
#define WHH_LD 1032  // 1024 + 8 pad

typedef _Float16 f16x8 __attribute__((ext_vector_type(8)));
typedef float f32x4 __attribute__((ext_vector_type(4)));

__device__ __forceinline__ float fast_sigmoid(float x) {
    return 1.0f / (1.0f + __expf(-x));
}
__device__ __forceinline__ float fast_tanh(float x) {
    return 1.0f - 2.0f / (__expf(2.0f * x) + 1.0f);
}

struct Params {
    const float *ehid, *Wih, *Whh, *bih, *bhh, *Wout, *bout;
    const float *Wm1, *bm1, *Wm2, *bm2, *Wc1, *bc1, *Wc2, *bc2;
    _Float16 *WoutH, *Wm1H, *Wc1H;
    float *h32; _Float16 *h16; _Float16 *outs;
    int *bar; int *flagA; int *flagB; float *dout;
};

// One-shot sense-reversing grid barrier (startup only).
__device__ __forceinline__ void gbar(int* bar) {
    __syncthreads();
    if (threadIdx.x == 0) {
        int g = __hip_atomic_load(bar + 32, __ATOMIC_RELAXED, __HIP_MEMORY_SCOPE_AGENT);
        int a = __hip_atomic_fetch_add(bar, 1, __ATOMIC_RELEASE, __HIP_MEMORY_SCOPE_AGENT);
        if (a == NWG - 1) {
            __hip_atomic_store(bar, 0, __ATOMIC_RELAXED, __HIP_MEMORY_SCOPE_AGENT);
            __hip_atomic_fetch_add(bar + 32, 1, __ATOMIC_RELEASE, __HIP_MEMORY_SCOPE_AGENT);
        } else {
            while (__hip_atomic_load(bar + 32, __ATOMIC_RELAXED, __HIP_MEMORY_SCOPE_AGENT) == g) {
                __builtin_amdgcn_s_sleep(2);
            }
        }
        __builtin_amdgcn_fence(__ATOMIC_ACQUIRE, "agent");
    }
    __syncthreads();
}

// Wait until all 64 flags of a group reach `target`.
// ONLY wave 0 polls: 64 lanes x 4B relaxed loads coalesce into 4 line
// requests per poll; s_sleep(16) (~0.4us) throttles the request rate.
// Then one acquire fence (single buffer_inv) by thread 0, barrier-fenced.
__device__ __forceinline__ void wait_grp(const int* flags, int target) {
    if (threadIdx.x < 64) {
        while (__hip_atomic_load(flags + threadIdx.x, __ATOMIC_RELAXED,
                                 __HIP_MEMORY_SCOPE_AGENT) < target)
            __builtin_amdgcn_s_sleep(16);
    }
    __syncthreads();                 // poll success visible to all waves
    if (threadIdx.x == 0)
        __builtin_amdgcn_fence(__ATOMIC_ACQUIRE, "agent");  // one L2 inv
    __syncthreads();                 // inv done before anyone reads
    asm volatile("" ::: "memory");
}

// Publish: compiler emits s_waitcnt vmcnt(0) before s_barrier, so all
// waves' stores are in L2; thread0's RELEASE store emits one buffer_wbl2
// (publishes the XCD L2) + the flag store.
__device__ __forceinline__ void set_flag(int* flag, int val) {
    __syncthreads();
    if (threadIdx.x == 0)
        __hip_atomic_store(flag, val, __ATOMIC_RELEASE, __HIP_MEMORY_SCOPE_AGENT);
}

__global__ __launch_bounds__(NTHR, 1) void gru_persistent(Params p) {
    __shared__ __align__(16) char smraw[3 * 16 * WIH_LD * 2 + 3 * 16 * WHH_LD * 2];
    __shared__ float red[2 * 16 * 16];
    _Float16* wih_s = (_Float16*)smraw;
    _Float16* whh_s = (_Float16*)(smraw + 3 * 16 * WIH_LD * 2);
    _Float16* hid_s = (_Float16*)smraw;  // heads overlay

    const int w = blockIdx.x;
    const int wave = threadIdx.x >> 6;
    const int lane = threadIdx.x & 63;
    const int l15 = lane & 15;
    const int kq = lane >> 4;

    // ---- prep: fp16 conversions (grid-stride over all WGs) ----
    {
        const int tid = w * NTHR + threadIdx.x;
        const int nth = NWG * NTHR;
        for (int i = tid; i < INP * HID / 4; i += nth) {
            float4 v = ((const float4*)p.Wout)[i];
            _Float16* d = p.WoutH + i * 4;
            d[0] = (_Float16)v.x; d[1] = (_Float16)v.y; d[2] = (_Float16)v.z; d[3] = (_Float16)v.w;
        }
        for (int i = tid; i < 128 * INP / 4; i += nth) {
            float4 v = ((const float4*)p.Wm1)[i];
            _Float16* d = p.Wm1H + i * 4;
            d[0] = (_Float16)v.x; d[1] = (_Float16)v.y; d[2] = (_Float16)v.z; d[3] = (_Float16)v.w;
            float4 u = ((const float4*)p.Wc1)[i];
            _Float16* e = p.Wc1H + i * 4;
            e[0] = (_Float16)u.x; e[1] = (_Float16)u.y; e[2] = (_Float16)u.z; e[3] = (_Float16)u.w;
        }
        for (int i = tid; i < BATCH * HID / 4; i += nth) {
            float4 v = ((const float4*)p.ehid)[i];
            ((float4*)p.h32)[i] = v;
            _Float16* d = p.h16 + i * 4;
            d[0] = (_Float16)v.x; d[1] = (_Float16)v.y; d[2] = (_Float16)v.z; d[3] = (_Float16)v.w;
        }
    }

    // ---- load this WG's gate-weight slice into LDS (fp32 -> fp16) ----
    const int jj = w >> 2;   // 0..63: 16-col slice of H
    const int b4 = w & 3;    // 0..3 : 64-row group of B  (= rowgroup g)
    for (int i = threadIdx.x; i < 3 * 16 * (INP / 4); i += NTHR) {
        int gi = i / (16 * (INP / 4));
        int rr = (i / (INP / 4)) % 16;
        int kk = (i % (INP / 4)) * 4;
        float4 v = *(const float4*)(p.Wih + ((size_t)(gi * HID + jj * 16 + rr)) * INP + kk);
        _Float16* d = &wih_s[(gi * 16 + rr) * WIH_LD + kk];
        d[0] = (_Float16)v.x; d[1] = (_Float16)v.y; d[2] = (_Float16)v.z; d[3] = (_Float16)v.w;
    }
    for (int i = threadIdx.x; i < 3 * 16 * (HID / 4); i += NTHR) {
        int gi = i / (16 * (HID / 4));
        int rr = (i / (HID / 4)) % 16;
        int kk = (i % (HID / 4)) * 4;
        float4 v = *(const float4*)(p.Whh + ((size_t)(gi * HID + jj * 16 + rr)) * HID + kk);
        _Float16* d = &whh_s[(gi * 16 + rr) * WHH_LD + kk];
        d[0] = (_Float16)v.x; d[1] = (_Float16)v.y; d[2] = (_Float16)v.z; d[3] = (_Float16)v.w;
    }

    gbar(p.bar);  // startup: prep + LDS slices ready everywhere

    // hoisted per-lane constants
    const int jc = jj * 16 + l15;
    const float brr = p.bih[jc] + p.bhh[jc];
    const float bzz = p.bih[HID + jc] + p.bhh[HID + jc];
    const float bin = p.bih[2 * HID + jc];
    const float bhn = p.bhh[2 * HID + jc];
    const int grow  = b4 * 64 + wave * 16 + l15;
    const int gcrow = b4 * 64 + wave * 16 + kq * 4;

    const int ort = w >> 4;                           // outproj: 16-row tile
    const int oct = w & 15;                           // outproj: 32-col tile
    const int og  = w >> 6;                           // outproj rowgroup (ort>>2)
    const int csub = wave & 1;
    const int khalf = wave >> 1;
    const int orow = ort * 16 + l15;
    const int ocol = oct * 32 + csub * 16 + l15;
    const float obout = p.bout[ocol];

    int* myFlagA = p.flagA + b4 * 64 + jj;                       // gates producer flag
    int* myFlagB = p.flagB + og * 64 + (ort & 3) * 16 + oct;     // outproj producer flag
    const int* grpFlagB = p.flagB + b4 * 64;                     // gates consumer group
    const int* grpFlagA = p.flagA + og * 64;                     // outproj consumer group

    for (int t = 0; t < SEQ; ++t) {
        const int cur = t & 1, nxt = 1 - cur;
        const float*    h32p = p.h32 + (size_t)cur * BATCH * HID;
        float*          h32n = p.h32 + (size_t)nxt * BATCH * HID;
        const _Float16* h16p = p.h16 + (size_t)cur * BATCH * HID;
        _Float16*       h16n = p.h16 + (size_t)nxt * BATCH * HID;

        // ---- phase A: gates (needs outs(t-1) of rowgroup b4) ----
        if (t > 0) wait_grp(grpFlagB, t);

        f32x4 ar = {0.f,0.f,0.f,0.f}, az = {0.f,0.f,0.f,0.f};
        f32x4 ai = {0.f,0.f,0.f,0.f}, ah = {0.f,0.f,0.f,0.f};
        if (t > 0) {
            const _Float16* xp = p.outs + ((size_t)grow * SEQ + (t - 1)) * INP + kq * 8;
            #pragma unroll 4
            for (int kk = 0; kk < INP; kk += 32) {
                f16x8 a = *(const f16x8*)(xp + kk);
                #pragma unroll
                for (int q = 0; q < 8; ++q) a[q] = a[q] > (_Float16)0.f ? a[q] : (_Float16)0.f;
                f16x8 br = *(const f16x8*)&wih_s[(0 * 16 + l15) * WIH_LD + kk + kq * 8];
                f16x8 bz = *(const f16x8*)&wih_s[(1 * 16 + l15) * WIH_LD + kk + kq * 8];
                f16x8 bn = *(const f16x8*)&wih_s[(2 * 16 + l15) * WIH_LD + kk + kq * 8];
                ar = __builtin_amdgcn_mfma_f32_16x16x32_f16(a, br, ar, 0, 0, 0);
                az = __builtin_amdgcn_mfma_f32_16x16x32_f16(a, bz, az, 0, 0, 0);
                ai = __builtin_amdgcn_mfma_f32_16x16x32_f16(a, bn, ai, 0, 0, 0);
            }
        }
        {
            const _Float16* hp = h16p + (size_t)grow * HID + kq * 8;
            #pragma unroll 4
            for (int kk = 0; kk < HID; kk += 32) {
                f16x8 a = *(const f16x8*)(hp + kk);
                f16x8 br = *(const f16x8*)&whh_s[(0 * 16 + l15) * WHH_LD + kk + kq * 8];
                f16x8 bz = *(const f16x8*)&whh_s[(1 * 16 + l15) * WHH_LD + kk + kq * 8];
                f16x8 bn = *(const f16x8*)&whh_s[(2 * 16 + l15) * WHH_LD + kk + kq * 8];
                ar = __builtin_amdgcn_mfma_f32_16x16x32_f16(a, br, ar, 0, 0, 0);
                az = __builtin_amdgcn_mfma_f32_16x16x32_f16(a, bz, az, 0, 0, 0);
                ah = __builtin_amdgcn_mfma_f32_16x16x32_f16(a, bn, ah, 0, 0, 0);
            }
        }
        #pragma unroll
        for (int i = 0; i < 4; ++i) {
            int r = gcrow + i;
            float rr = fast_sigmoid(ar[i] + brr);
            float zz = fast_sigmoid(az[i] + bzz);
            float nn = fast_tanh(ai[i] + bin + rr * (ah[i] + bhn));
            float hold = h32p[(size_t)r * HID + jc];
            float hv = (1.0f - zz) * nn + zz * hold;
            h32n[(size_t)r * HID + jc] = hv;
            h16n[(size_t)r * HID + jc] = (_Float16)hv;
        }

        set_flag(myFlagA, t + 1);          // h'(t) rows of group b4, slice jj: done

        // ---- phase B: outproj (needs h'(t) of rowgroup og) ----
        wait_grp(grpFlagA, t + 1);
        {
            f32x4 acc = {0.f,0.f,0.f,0.f};
            const _Float16* ap = h16n + (size_t)orow * HID + khalf * 512 + kq * 8;
            const _Float16* bp = p.WoutH + (size_t)ocol * HID + khalf * 512 + kq * 8;
            #pragma unroll 4
            for (int kk = 0; kk < 512; kk += 32) {
                f16x8 a = *(const f16x8*)(ap + kk);
                f16x8 b = *(const f16x8*)(bp + kk);
                acc = __builtin_amdgcn_mfma_f32_16x16x32_f16(a, b, acc, 0, 0, 0);
            }
            if (khalf == 1) {
                #pragma unroll
                for (int i = 0; i < 4; ++i)
                    red[(csub * 16 + kq * 4 + i) * 16 + l15] = acc[i];
            }
            __syncthreads();
            if (khalf == 0) {
                #pragma unroll
                for (int i = 0; i < 4; ++i) {
                    float v = acc[i] + red[(csub * 16 + kq * 4 + i) * 16 + l15];
                    p.outs[((size_t)(ort * 16 + kq * 4 + i) * SEQ + t) * INP + ocol] =
                        (_Float16)(v + obout);
                }
            }
        }

        set_flag(myFlagB, t + 1);          // outs(t) tile (ort,oct): done
    }

    // ---- heads: WG w handles batch element b = w ----
    {
        const int b = w;
        wait_grp(p.flagB + (b >> 6) * 64, SEQ);   // all outs rows of b's group
        const size_t rowbase = (size_t)b * SEQ;
        for (int head = 0; head < 2; ++head) {
            const _Float16* W1 = head ? p.Wc1H : p.Wm1H;
            const float* b1 = head ? p.bc1 : p.bm1;
            f32x4 acc[2][8];
            #pragma unroll
            for (int rf = 0; rf < 2; ++rf)
                #pragma unroll
                for (int ct = 0; ct < 8; ++ct) acc[rf][ct] = (f32x4){0.f,0.f,0.f,0.f};
            for (int kk = 0; kk < INP; kk += 32) {
                f16x8 a0 = *(const f16x8*)(p.outs + (rowbase + wave * 32 + l15) * INP + kk + kq * 8);
                f16x8 a1 = *(const f16x8*)(p.outs + (rowbase + wave * 32 + 16 + l15) * INP + kk + kq * 8);
                #pragma unroll
                for (int ct = 0; ct < 8; ++ct) {
                    f16x8 bb = *(const f16x8*)(W1 + (size_t)(ct * 16 + l15) * INP + kk + kq * 8);
                    acc[0][ct] = __builtin_amdgcn_mfma_f32_16x16x32_f16(a0, bb, acc[0][ct], 0, 0, 0);
                    acc[1][ct] = __builtin_amdgcn_mfma_f32_16x16x32_f16(a1, bb, acc[1][ct], 0, 0, 0);
                }
            }
            __syncthreads();
            #pragma unroll
            for (int rf = 0; rf < 2; ++rf) {
                int rl = wave * 32 + rf * 16 + kq * 4;
                #pragma unroll
                for (int ct = 0; ct < 8; ++ct) {
                    int col = ct * 16 + l15;
                    float bb1 = b1[col];
                    #pragma unroll
                    for (int i = 0; i < 4; ++i) {
                        float v = acc[rf][ct][i] + bb1;
                        hid_s[(rl + i) * 136 + col] = (_Float16)(v > 0.f ? v : 0.f);
                    }
                }
            }
            __syncthreads();
            if (threadIdx.x < 128) {
                int srow = threadIdx.x;
                if (head == 0) {
                    float a0 = p.bm2[0], a1 = p.bm2[1], a2 = p.bm2[2];
                    for (int k = 0; k < 128; ++k) {
                        float hv = (float)hid_s[srow * 136 + k];
                        a0 += hv * p.Wm2[k];
                        a1 += hv * p.Wm2[128 + k];
                        a2 += hv * p.Wm2[256 + k];
                    }
                    size_t o = ((size_t)b * 128 + srow) * 3;
                    p.dout[o] = a0; p.dout[o + 1] = a1; p.dout[o + 2] = a2;
                } else {
                    float a[6];
                    #pragma unroll
                    for (int m = 0; m < 6; ++m) a[m] = p.bc2[m];
                    for (int k = 0; k < 128; ++k) {
                        float hv = (float)hid_s[srow * 136 + k];
                        #pragma unroll
                        for (int m = 0; m < 6; ++m) a[m] += hv * p.Wc2[m * 128 + k];
                    }
                    size_t o = (size_t)BATCH * SEQ * 3 + ((size_t)b * 128 + srow) * 6;
                    #pragma unroll
                    for (int m = 0; m < 6; ++m) p.dout[o + m] = a[m];
                }
            }
            __syncthreads();
        }
    }
}

extern "C" void kernel_launch(void* const* d_in, const int* in_sizes, int n_in,
                              void* d_out, int out_size, void* d_ws, size_t ws_size,
                              hipStream_t stream) {
    (void)in_sizes; (void)n_in; (void)out_size; (void)ws_size;
    Params prm;
    prm.ehid = (const float*)d_in[1];
    prm.Wih  = (const float*)d_in[2];
    prm.Whh  = (const float*)d_in[3];
    prm.bih  = (const float*)d_in[4];
    prm.bhh  = (const float*)d_in[5];
    prm.Wout = (const float*)d_in[6];
    prm.bout = (const float*)d_in[7];
    prm.Wm1  = (const float*)d_in[8];
    prm.bm1  = (const float*)d_in[9];
    prm.Wm2  = (const float*)d_in[10];
    prm.bm2  = (const float*)d_in[11];
    prm.Wc1  = (const float*)d_in[12];
    prm.bc1  = (const float*)d_in[13];
    prm.Wc2  = (const float*)d_in[14];
    prm.bc2  = (const float*)d_in[15];
    prm.dout = (float*)d_out;

    char* ws = (char*)d_ws;
    prm.bar   = (int*)ws;                                  // 256 B   (startup barrier)
    prm.flagA = (int*)(ws + 256);                          // 1024 B  (256 gate flags)
    prm.flagB = (int*)(ws + 1280);                         // 1024 B  (256 outproj flags)
    prm.WoutH = (_Float16*)(ws + 4096);                    // 1,048,576 B
    prm.Wm1H  = (_Float16*)(ws + 4096 + 1048576);          //   131,072 B
    prm.Wc1H  = (_Float16*)(ws + 4096 + 1179648);          //   131,072 B
    prm.h32   = (float*)   (ws + 4096 + 1310720);          // 2,097,152 B (double buf)
    prm.h16   = (_Float16*)(ws + 4096 + 3407872);          // 1,048,576 B (double buf)
    prm.outs  = (_Float16*)(ws + 4096 + 4456448);          // 33,554,432 B
    // total ~38.0 MB

    hipMemsetAsync(ws, 0, 2304, stream);  // zero barrier + flag state every launch
    void* args[] = { &prm };
    hipLaunchCooperativeKernel((void*)gru_persistent, dim3(NWG), dim3(NTHR),
                               args, 0, stream);
}